// Round 5
// baseline (311.840 us; speedup 1.0000x reference)
//
#include <hip/hip_runtime.h>
#include <math.h>

#define B_  8
#define T_  2048
#define S_  2048
#define D_  512

typedef _Float16 half8   __attribute__((ext_vector_type(8)));
typedef _Float16 half4_t __attribute__((ext_vector_type(4)));
typedef float    floatx4 __attribute__((ext_vector_type(4)));

__device__ __forceinline__ floatx4 mfma16(half8 a, half8 b, floatx4 c) {
  return __builtin_amdgcn_mfma_f32_16x16x32_f16(a, b, c, 0, 0, 0);
}

// async global->LDS, 16B per lane; lds base must be wave-uniform (HW adds lane*16)
__device__ __forceinline__ void async16(void* lds, const void* g) {
  __builtin_amdgcn_global_load_lds(
      (const __attribute__((address_space(1))) void*)g,
      (__attribute__((address_space(3))) void*)lds, 16, 0, 0);
}

// LDS-visibility barrier: drains lgkmcnt ONLY, so the global_load_lds
// prefetch stays in flight across it (drained by __syncthreads at tile end).
__device__ __forceinline__ void bar_lds() {
  __builtin_amdgcn_sched_barrier(0);
  asm volatile("s_waitcnt lgkmcnt(0)" ::: "memory");
  __builtin_amdgcn_s_barrier();
  __builtin_amdgcn_sched_barrier(0);
}

// ---------------------------------------------------------------------------
// Kernel 1: Vt[b][d][s] = (fp16) attn[b][s][d]
// ---------------------------------------------------------------------------
__global__ __launch_bounds__(256) void transpose_cast_kernel(
    const float* __restrict__ attn, _Float16* __restrict__ Vt) {
  __shared__ _Float16 tile[32][33];
  const int tx = threadIdx.x, ty = threadIdx.y;
  const int b = blockIdx.z, s0 = blockIdx.y * 32, d0 = blockIdx.x * 32;
  const float* src = attn + ((size_t)b * S_ + s0) * D_ + d0;
#pragma unroll
  for (int i = 0; i < 4; ++i) {
    int s = ty + i * 8;
    tile[tx][s] = (_Float16)src[(size_t)s * D_ + tx];
  }
  __syncthreads();
  _Float16* dst = Vt + ((size_t)b * D_ + d0) * S_ + s0;
#pragma unroll
  for (int i = 0; i < 4; ++i) {
    int d = ty + i * 8;
    dst[(size_t)d * S_ + tx] = tile[d][tx];
  }
}

// ---------------------------------------------------------------------------
// Kernel 2: K16[i][e] = (fp16)( sum_d attn[i][d] * W[e][d] + bias[e] )
// ---------------------------------------------------------------------------
__global__ __launch_bounds__(512, 2) void keys_gemm_kernel(
    const float* __restrict__ X, const float* __restrict__ W,
    const float* __restrict__ bias, _Float16* __restrict__ K16) {
  __shared__ alignas(16) _Float16 Xs[128][72];
  __shared__ alignas(16) _Float16 Ws[128][72];
  const int t = threadIdx.x;
  const int wave = t >> 6, lane = t & 63, q = lane >> 4, n = lane & 15;
  const int wm = wave >> 2, wn = wave & 3;
  const int m0 = blockIdx.x * 128, n0 = blockIdx.y * 128;

  floatx4 acc[4][2];
#pragma unroll
  for (int i = 0; i < 4; ++i)
#pragma unroll
    for (int j = 0; j < 2; ++j) {
      floatx4 z = {0.f, 0.f, 0.f, 0.f};
      acc[i][j] = z;
    }

  for (int kc = 0; kc < 8; ++kc) {
    const int k0 = kc * 64;
#pragma unroll
    for (int i = 0; i < 4; ++i) {
      int seg = i * 512 + t;
      int row = seg >> 4, c4 = (seg & 15) * 4;
      floatx4 xv = *(const floatx4*)&X[(size_t)(m0 + row) * D_ + k0 + c4];
      floatx4 wv = *(const floatx4*)&W[(size_t)(n0 + row) * D_ + k0 + c4];
      half4_t xh, wh;
#pragma unroll
      for (int j = 0; j < 4; ++j) { xh[j] = (_Float16)xv[j]; wh[j] = (_Float16)wv[j]; }
      *(half4_t*)&Xs[row][c4] = xh;
      *(half4_t*)&Ws[row][c4] = wh;
    }
    __syncthreads();
#pragma unroll
    for (int kk = 0; kk < 2; ++kk) {
      half8 a[4], bb[2];
#pragma unroll
      for (int mt = 0; mt < 4; ++mt)
        a[mt] = *(const half8*)&Xs[wm * 64 + mt * 16 + n][kk * 32 + q * 8];
#pragma unroll
      for (int nt = 0; nt < 2; ++nt)
        bb[nt] = *(const half8*)&Ws[wn * 32 + nt * 16 + n][kk * 32 + q * 8];
#pragma unroll
      for (int mt = 0; mt < 4; ++mt)
#pragma unroll
        for (int nt = 0; nt < 2; ++nt)
          acc[mt][nt] = mfma16(a[mt], bb[nt], acc[mt][nt]);
    }
    __syncthreads();
  }

#pragma unroll
  for (int nt = 0; nt < 2; ++nt) {
    int col = n0 + wn * 32 + nt * 16 + n;
    float bv = bias[col];
#pragma unroll
    for (int mt = 0; mt < 4; ++mt)
#pragma unroll
      for (int r = 0; r < 4; ++r) {
        int row = m0 + wm * 64 + mt * 16 + q * 4 + r;
        K16[(size_t)row * D_ + col] = (_Float16)(acc[mt][nt][r] + bv);
      }
  }
}

// ---------------------------------------------------------------------------
// Kernel 3: flash attention — 512 thr / 8 waves, BM=64, BN=32.
//   Wave pair (rg, h): QK^T s-split, PV d-split (R1 structure, 189 us).
//   Kept from R3: strength-reduced addressing (precomputed LDS bases + imm
//   offsets; u32 DMA offsets bumped by constants), defer-max THR=8.
//   REMOVED: s_setprio — m190-style regression in this near-lockstep
//   structure (pair bar_lds keeps SIMD-co-resident waves in phase; prio
//   boost starves the other wave's LDS issue instead of filling a gap).
// ---------------------------------------------------------------------------
__global__ __launch_bounds__(512, 2) void flash_kernel(
    const float* __restrict__ Qf, const _Float16* __restrict__ K16,
    const _Float16* __restrict__ Vt, float* __restrict__ out) {
  __shared__ alignas(16) _Float16 Klds[2][32][512];
  __shared__ alignas(16) _Float16 Vlds[2][512][32];
  __shared__ alignas(16) _Float16 Pscr[4][16][40];  // per-row-group shared P
  __shared__ float Mscr[4][2][16];                  // per-(rg,h) row maxes

  const int t = threadIdx.x;
  const int w = t >> 6, lane = t & 63, qd = lane >> 4, n = lane & 15;
  const int n7 = n & 7;
  const int rg = w >> 1, h = w & 1;
  const int bid = blockIdx.x;
  const int b = bid & 7, t0 = (bid >> 3) * 64;

  const char* Kb = (const char*)(K16 + (size_t)b * S_ * D_);
  const char* Vb = (const char*)(Vt + (size_t)b * D_ * S_);

  const int vsw = (lane & 3) ^ ((lane >> 3) & 3);  // staging V source s-chunk
  const int ccV = qd ^ ((n >> 1) & 3);             // V read slot

  // ---- precomputed LDS read bases (byte offsets) ----
  // K slot (kk*4+qd)^n7 decomposes: bits0-1 = qd^(n7&3); bit2 = (kk&1)^ks;
  // bits3+ = kk>>1  (ks = n7>>2). Two bases (even/odd kk) + imm (kk>>1)*128.
  const int ks = n7 >> 2;
  const int kq = (qd ^ (n7 & 3)) * 16;
  const int krow_b = (h * 16 + n) * 1024;
  const char* KL = (const char*)Klds;
  const char* kbe0 = KL + krow_b + kq + ks * 64;        // even kk, buf 0
  const char* kbo0 = KL + krow_b + kq + 64 - ks * 64;   // odd  kk, buf 0
  // V read: addr = cur*32768 + h*16384 + n*64 + ccV*16 + ng*1024
  const char* VL = (const char*)Vlds;
  const char* vb0 = VL + h * 16384 + n * 64 + ccV * 16;
  const _Float16* prd = &Pscr[rg][n][qd * 8];           // P A-frag read base

  // ---- per-lane global DMA offsets (u32, bumped by constants per tile) ----
  unsigned int koff[4], voff[4];
#pragma unroll
  for (int i = 0; i < 4; ++i) {
    int row = w * 4 + i;
    koff[i] = (unsigned int)((row * 512 + (lane ^ (row & 7)) * 8) * 2);
    voff[i] = (unsigned int)(((row * 16 + (lane >> 2)) * S_ + vsw * 8) * 2);
  }

  // ---- Q -> registers (row-group's 16 rows, full D; pair-redundant) ----
  half8 qreg[16];
  {
    const float* qrow = Qf + ((size_t)b * T_ + t0 + rg * 16 + n) * D_;
#pragma unroll
    for (int kk = 0; kk < 16; ++kk) {
      floatx4 v0 = *(const floatx4*)&qrow[kk * 32 + qd * 8];
      floatx4 v1 = *(const floatx4*)&qrow[kk * 32 + qd * 8 + 4];
      half8 hv;
#pragma unroll
      for (int j = 0; j < 4; ++j) { hv[j] = (_Float16)v0[j]; hv[j + 4] = (_Float16)v1[j]; }
      qreg[kk] = hv;
    }
  }

  floatx4 O[17];   // [0..15] = wave's 256-d half, [16] = l (ones column)
#pragma unroll
  for (int ng = 0; ng < 17; ++ng) {
    floatx4 z = {0.f, 0.f, 0.f, 0.f};
    O[ng] = z;
  }
  float m_st[4];
#pragma unroll
  for (int r = 0; r < 4; ++r) m_st[r] = -1e30f;

  half8 ones8;
#pragma unroll
  for (int j = 0; j < 8; ++j) ones8[j] = (_Float16)1.0f;

  // ---- prologue staging: K[0], V[0] ----
#pragma unroll
  for (int i = 0; i < 4; ++i) {
    int row = w * 4 + i;
    async16(&Klds[0][row][0], Kb + koff[i]);
    async16(&Vlds[0][row * 16][0], Vb + voff[i]);
    koff[i] += 32768;   // next K tile: +32 rows * 512 halves * 2B
    voff[i] += 64;      // next V tile: +32 s * 2B
  }
  __syncthreads();

  for (int st = 0; st < S_ / 32; ++st) {
    const int cur = st & 1, nxt = cur ^ 1;

    // ---- prefetch next K+V tile (in flight across the pair barriers) ----
    if (st < S_ / 32 - 1) {
#pragma unroll
      for (int i = 0; i < 4; ++i) {
        int row = w * 4 + i;
        async16(&Klds[nxt][row][0], Kb + koff[i]);
        async16(&Vlds[nxt][row * 16][0], Vb + voff[i]);
        koff[i] += 32768;
        voff[i] += 64;
      }
    }

    // ---- QK^T: wave's 16 rows x its 16 cols, K=512 (2 indep chains) ----
    const char* ke = (cur ? kbe0 + 32768 : kbe0);
    const char* ko = (cur ? kbo0 + 32768 : kbo0);
    floatx4 Sa = {0.f, 0.f, 0.f, 0.f}, Sb = Sa;
#pragma unroll
    for (int j = 0; j < 8; ++j) {
      Sa = mfma16(qreg[2 * j],     *(const half8*)(ke + j * 128), Sa);
      Sb = mfma16(qreg[2 * j + 1], *(const half8*)(ko + j * 128), Sb);
    }
    floatx4 Sc = Sa + Sb;

    // ---- local row-max over wave's 16 cols; publish per-half max ----
#pragma unroll
    for (int r = 0; r < 4; ++r) {
      float v = Sc[r];
      v = fmaxf(v, __shfl_xor(v, 1, 16));
      v = fmaxf(v, __shfl_xor(v, 2, 16));
      v = fmaxf(v, __shfl_xor(v, 4, 16));
      v = fmaxf(v, __shfl_xor(v, 8, 16));
      if (n == qd * 4 + r) Mscr[rg][h][n] = v;  // row qd*4+r == n
    }
    bar_lds();  // (1) Mscr visible across the wave pair

    // ---- defer-max (THR=8): update m/rescale only on large growth ----
    float pm[4], need = 0.f;
#pragma unroll
    for (int r = 0; r < 4; ++r) {
      int row = qd * 4 + r;
      pm[r] = fmaxf(Mscr[rg][0][row], Mscr[rg][1][row]);
      need = fmaxf(need, pm[r] - m_st[r]);
    }
    if (__any(need > 8.f)) {
#pragma unroll
      for (int r = 0; r < 4; ++r) {
        float mn = fmaxf(m_st[r], pm[r]);
        float al = __expf(m_st[r] - mn);
        m_st[r] = mn;
#pragma unroll
        for (int ng = 0; ng < 17; ++ng) O[ng][r] *= al;
      }
    }

    // ---- P = exp(S - m) -> shared scratch (wave writes its 16 cols) ----
#pragma unroll
    for (int r = 0; r < 4; ++r) {
      float p = __expf(Sc[r] - m_st[r]);   // <= e^8, fp16-safe
      Pscr[rg][qd * 4 + r][h * 16 + n] = (_Float16)p;
    }
    bar_lds();  // (2) both halves of P visible

    half8 av = *(const half8*)prd;

    // ---- PV: O[16 rows x 256-d half] += P(16x32) @ V(32x256), + l ----
    const char* vbp = (cur ? vb0 + 32768 : vb0);
#pragma unroll
    for (int ng = 0; ng < 16; ++ng) {
      O[ng] = mfma16(av, *(const half8*)(vbp + ng * 1024), O[ng]);
    }
    O[16] = mfma16(av, ones8, O[16]);

    if (st < S_ / 32 - 1) __syncthreads();  // (3) swap buffers (drains prefetch)
  }

  // ---- epilogue: out = O / l for this wave's 256-d half ----
  float* ob = out + ((size_t)b * T_ + t0 + rg * 16) * D_ + h * 256;
#pragma unroll
  for (int r = 0; r < 4; ++r) {
    float inv = 1.f / O[16][r];
    const size_t rowoff = (size_t)(qd * 4 + r) * D_;
#pragma unroll
    for (int ng = 0; ng < 16; ++ng)
      ob[rowoff + ng * 16 + n] = O[ng][r] * inv;
  }
}

// ---------------------------------------------------------------------------
extern "C" void kernel_launch(void* const* d_in, const int* in_sizes, int n_in,
                              void* d_out, int out_size, void* d_ws, size_t ws_size,
                              hipStream_t stream) {
  (void)in_sizes; (void)n_in; (void)out_size; (void)ws_size;
  const float* main_in = (const float*)d_in[0];   // [B,T,D]
  const float* attn_in = (const float*)d_in[1];   // [B,S,D]
  const float* W_f     = (const float*)d_in[2];   // [D,D]
  const float* b_f     = (const float*)d_in[3];   // [D]
  float* out = (float*)d_out;                     // [B,T,D] fp32

  _Float16* K16 = (_Float16*)d_ws;                       // [B*S, D] fp16
  _Float16* Vt  = K16 + (size_t)B_ * S_ * D_;            // [B, D, S] fp16

  transpose_cast_kernel<<<dim3(D_ / 32, S_ / 32, B_), dim3(32, 8, 1), 0, stream>>>(
      attn_in, Vt);
  keys_gemm_kernel<<<dim3((B_ * S_) / 128, D_ / 128), 512, 0, stream>>>(
      attn_in, W_f, b_f, K16);
  flash_kernel<<<(B_ * T_) / 64, 512, 0, stream>>>(main_in, K16, Vt, out);
}

// Round 6
// 288.166 us; speedup vs baseline: 1.0822x; 1.0822x over previous
//
#include <hip/hip_runtime.h>
#include <math.h>

#define B_  8
#define T_  2048
#define S_  2048
#define D_  512

typedef _Float16 half8   __attribute__((ext_vector_type(8)));
typedef _Float16 half4_t __attribute__((ext_vector_type(4)));
typedef float    floatx4 __attribute__((ext_vector_type(4)));

__device__ __forceinline__ floatx4 mfma16(half8 a, half8 b, floatx4 c) {
  return __builtin_amdgcn_mfma_f32_16x16x32_f16(a, b, c, 0, 0, 0);
}

// async global->LDS, 16B per lane; lds base must be wave-uniform (HW adds lane*16)
__device__ __forceinline__ void async16(void* lds, const void* g) {
  __builtin_amdgcn_global_load_lds(
      (const __attribute__((address_space(1))) void*)g,
      (__attribute__((address_space(3))) void*)lds, 16, 0, 0);
}

// LDS-visibility barrier: drains lgkmcnt ONLY, so the global_load_lds
// prefetch stays in flight across it (drained by __syncthreads at tile end).
__device__ __forceinline__ void bar_lds() {
  __builtin_amdgcn_sched_barrier(0);
  asm volatile("s_waitcnt lgkmcnt(0)" ::: "memory");
  __builtin_amdgcn_s_barrier();
  __builtin_amdgcn_sched_barrier(0);
}

// ---------------------------------------------------------------------------
// Kernel 1: Vt[b][d][s] = (fp16) attn[b][s][d]
// ---------------------------------------------------------------------------
__global__ __launch_bounds__(256) void transpose_cast_kernel(
    const float* __restrict__ attn, _Float16* __restrict__ Vt) {
  __shared__ _Float16 tile[32][33];
  const int tx = threadIdx.x, ty = threadIdx.y;
  const int b = blockIdx.z, s0 = blockIdx.y * 32, d0 = blockIdx.x * 32;
  const float* src = attn + ((size_t)b * S_ + s0) * D_ + d0;
#pragma unroll
  for (int i = 0; i < 4; ++i) {
    int s = ty + i * 8;
    tile[tx][s] = (_Float16)src[(size_t)s * D_ + tx];
  }
  __syncthreads();
  _Float16* dst = Vt + ((size_t)b * D_ + d0) * S_ + s0;
#pragma unroll
  for (int i = 0; i < 4; ++i) {
    int d = ty + i * 8;
    dst[(size_t)d * S_ + tx] = tile[d][tx];
  }
}

// ---------------------------------------------------------------------------
// Kernel 2: K16[i][e] = (fp16)( sum_d attn[i][d] * W[e][d] + bias[e] )
// ---------------------------------------------------------------------------
__global__ __launch_bounds__(512, 2) void keys_gemm_kernel(
    const float* __restrict__ X, const float* __restrict__ W,
    const float* __restrict__ bias, _Float16* __restrict__ K16) {
  __shared__ alignas(16) _Float16 Xs[128][72];
  __shared__ alignas(16) _Float16 Ws[128][72];
  const int t = threadIdx.x;
  const int wave = t >> 6, lane = t & 63, q = lane >> 4, n = lane & 15;
  const int wm = wave >> 2, wn = wave & 3;
  const int m0 = blockIdx.x * 128, n0 = blockIdx.y * 128;

  floatx4 acc[4][2];
#pragma unroll
  for (int i = 0; i < 4; ++i)
#pragma unroll
    for (int j = 0; j < 2; ++j) {
      floatx4 z = {0.f, 0.f, 0.f, 0.f};
      acc[i][j] = z;
    }

  for (int kc = 0; kc < 8; ++kc) {
    const int k0 = kc * 64;
#pragma unroll
    for (int i = 0; i < 4; ++i) {
      int seg = i * 512 + t;
      int row = seg >> 4, c4 = (seg & 15) * 4;
      floatx4 xv = *(const floatx4*)&X[(size_t)(m0 + row) * D_ + k0 + c4];
      floatx4 wv = *(const floatx4*)&W[(size_t)(n0 + row) * D_ + k0 + c4];
      half4_t xh, wh;
#pragma unroll
      for (int j = 0; j < 4; ++j) { xh[j] = (_Float16)xv[j]; wh[j] = (_Float16)wv[j]; }
      *(half4_t*)&Xs[row][c4] = xh;
      *(half4_t*)&Ws[row][c4] = wh;
    }
    __syncthreads();
#pragma unroll
    for (int kk = 0; kk < 2; ++kk) {
      half8 a[4], bb[2];
#pragma unroll
      for (int mt = 0; mt < 4; ++mt)
        a[mt] = *(const half8*)&Xs[wm * 64 + mt * 16 + n][kk * 32 + q * 8];
#pragma unroll
      for (int nt = 0; nt < 2; ++nt)
        bb[nt] = *(const half8*)&Ws[wn * 32 + nt * 16 + n][kk * 32 + q * 8];
#pragma unroll
      for (int mt = 0; mt < 4; ++mt)
#pragma unroll
        for (int nt = 0; nt < 2; ++nt)
          acc[mt][nt] = mfma16(a[mt], bb[nt], acc[mt][nt]);
    }
    __syncthreads();
  }

#pragma unroll
  for (int nt = 0; nt < 2; ++nt) {
    int col = n0 + wn * 32 + nt * 16 + n;
    float bv = bias[col];
#pragma unroll
    for (int mt = 0; mt < 4; ++mt)
#pragma unroll
      for (int r = 0; r < 4; ++r) {
        int row = m0 + wm * 64 + mt * 16 + q * 4 + r;
        K16[(size_t)row * D_ + col] = (_Float16)(acc[mt][nt][r] + bv);
      }
  }
}

// ---------------------------------------------------------------------------
// Kernel 3: flash attention — 512 thr / 8 waves, BM=64, BN=32.
//   EXACT R1 structure (189 us known-good): wave pair (rg, h), QK^T s-split,
//   PV d-split; direct __shared__ array indexing (ds_read path — do NOT
//   strength-reduce through generic char* bases: pointer-select merges defeat
//   InferAddressSpaces and pessimize to flat loads; R4/R5 lost 17 us to this).
//   Single delta vs R1: defer-max THR=8 (skip m-update/O-rescale unless the
//   pair max grows > 8; P <= e^8 is fp16-safe, l/O fp32-safe).
// ---------------------------------------------------------------------------
__global__ __launch_bounds__(512, 2) void flash_kernel(
    const float* __restrict__ Qf, const _Float16* __restrict__ K16,
    const _Float16* __restrict__ Vt, float* __restrict__ out) {
  // Klds row = 32 chunks of 16B, chunk slot l holds source chunk (l ^ (srow&7))
  __shared__ alignas(16) _Float16 Klds[2][32][512];
  // Vlds row (d) = 4 chunks of 16B, slot c holds source s-chunk (c ^ ((d>>1)&3))
  __shared__ alignas(16) _Float16 Vlds[2][512][32];
  __shared__ alignas(16) _Float16 Pscr[4][16][40];  // per-row-group shared P
  __shared__ float Mscr[4][2][16];                  // per-(rg,h) row maxes

  const int t = threadIdx.x;
  const int w = t >> 6, lane = t & 63, qd = lane >> 4, n = lane & 15;
  const int n7 = n & 7;
  const int rg = w >> 1, h = w & 1;
  const int bid = blockIdx.x;
  const int b = bid & 7, t0 = (bid >> 3) * 64;

  const _Float16* Kb = K16 + (size_t)b * S_ * D_;
  const _Float16* Vb = Vt + (size_t)b * D_ * S_;

  const int vsw = (lane & 3) ^ ((lane >> 3) & 3);  // staging V source s-chunk
  const int ccV = qd ^ ((n >> 1) & 3);             // V read slot

  // ---- Q -> registers (row-group's 16 rows, full D; pair-redundant) ----
  half8 qreg[16];
  {
    const float* qrow = Qf + ((size_t)b * T_ + t0 + rg * 16 + n) * D_;
#pragma unroll
    for (int kk = 0; kk < 16; ++kk) {
      floatx4 v0 = *(const floatx4*)&qrow[kk * 32 + qd * 8];
      floatx4 v1 = *(const floatx4*)&qrow[kk * 32 + qd * 8 + 4];
      half8 hv;
#pragma unroll
      for (int j = 0; j < 4; ++j) { hv[j] = (_Float16)v0[j]; hv[j + 4] = (_Float16)v1[j]; }
      qreg[kk] = hv;
    }
  }

  floatx4 O[17];   // [0..15] = wave's 256-d half, [16] = l (ones column)
#pragma unroll
  for (int ng = 0; ng < 17; ++ng) {
    floatx4 z = {0.f, 0.f, 0.f, 0.f};
    O[ng] = z;
  }
  float m_st[4];
#pragma unroll
  for (int r = 0; r < 4; ++r) m_st[r] = -1e30f;

  half8 ones8;
#pragma unroll
  for (int j = 0; j < 8; ++j) ones8[j] = (_Float16)1.0f;

  // ---- prologue staging: K[0], V[0] (8 waves x 4 rows / 4 d-groups) ----
#pragma unroll
  for (int i = 0; i < 4; ++i) {
    int row = w * 4 + i;
    async16(&Klds[0][row][0], Kb + (size_t)row * D_ + ((lane ^ (row & 7)) * 8));
  }
#pragma unroll
  for (int i = 0; i < 4; ++i) {
    int d0 = (w * 4 + i) * 16;
    async16(&Vlds[0][d0][0], Vb + (size_t)(d0 + (lane >> 2)) * S_ + vsw * 8);
  }
  __syncthreads();

  for (int st = 0; st < S_ / 32; ++st) {
    const int cur = st & 1, nxt = cur ^ 1;
    const int s0 = st * 32;

    // ---- prefetch next K+V tile (in flight across the pair barriers) ----
    if (st < S_ / 32 - 1) {
#pragma unroll
      for (int i = 0; i < 4; ++i) {
        int row = w * 4 + i;
        async16(&Klds[nxt][row][0],
                Kb + (size_t)(s0 + 32 + row) * D_ + ((lane ^ (row & 7)) * 8));
      }
#pragma unroll
      for (int i = 0; i < 4; ++i) {
        int d0 = (w * 4 + i) * 16;
        async16(&Vlds[nxt][d0][0],
                Vb + (size_t)(d0 + (lane >> 2)) * S_ + s0 + 32 + vsw * 8);
      }
    }

    // ---- QK^T: rg's 16 rows x h's 16 cols, full K=512 (2 indep chains) ----
    floatx4 Sa = {0.f, 0.f, 0.f, 0.f}, Sb = Sa;
#pragma unroll
    for (int kk = 0; kk < 8; ++kk) {
      int slot = (kk * 4 + qd) ^ n7;
      half8 bk = *(const half8*)&Klds[cur][h * 16 + n][slot * 8];
      Sa = mfma16(qreg[kk], bk, Sa);
    }
#pragma unroll
    for (int kk = 8; kk < 16; ++kk) {
      int slot = (kk * 4 + qd) ^ n7;
      half8 bk = *(const half8*)&Klds[cur][h * 16 + n][slot * 8];
      Sb = mfma16(qreg[kk], bk, Sb);
    }
    floatx4 Sc = Sa + Sb;

    // ---- local row-max over this wave's 16 cols; publish per-half max ----
#pragma unroll
    for (int r = 0; r < 4; ++r) {
      float v = Sc[r];
      v = fmaxf(v, __shfl_xor(v, 1, 16));
      v = fmaxf(v, __shfl_xor(v, 2, 16));
      v = fmaxf(v, __shfl_xor(v, 4, 16));
      v = fmaxf(v, __shfl_xor(v, 8, 16));
      if (n == qd * 4 + r) Mscr[rg][h][n] = v;  // row qd*4+r == n
    }
    bar_lds();  // (1) Mscr visible across the wave pair

    // ---- combine halves; defer-max THR=8 (pair-consistent) ----
    float pm[4], need = 0.f;
#pragma unroll
    for (int r = 0; r < 4; ++r) {
      int row = qd * 4 + r;
      pm[r] = fmaxf(Mscr[rg][0][row], Mscr[rg][1][row]);
      need = fmaxf(need, pm[r] - m_st[r]);
    }
    if (__any(need > 8.f)) {
#pragma unroll
      for (int r = 0; r < 4; ++r) {
        float mn = fmaxf(m_st[r], pm[r]);
        float al = __expf(m_st[r] - mn);
        m_st[r] = mn;
#pragma unroll
        for (int ng = 0; ng < 17; ++ng) O[ng][r] *= al;
      }
    }

    // ---- P = exp(S - m) -> shared scratch (wave writes its 16 cols) ----
#pragma unroll
    for (int r = 0; r < 4; ++r) {
      float p = __expf(Sc[r] - m_st[r]);   // <= e^8, fp16-safe
      Pscr[rg][qd * 4 + r][h * 16 + n] = (_Float16)p;
    }
    bar_lds();  // (2) both halves of P visible

    half8 av = *(const half8*)&Pscr[rg][n][qd * 8];

    // ---- PV: O[16 rows x 256-d half] += P(16x32) @ V(32x256), + l ----
#pragma unroll
    for (int ng = 0; ng < 16; ++ng) {
      half8 bv = *(const half8*)&Vlds[cur][h * 256 + ng * 16 + n][ccV * 8];
      O[ng] = mfma16(av, bv, O[ng]);
    }
    O[16] = mfma16(av, ones8, O[16]);

    if (st < S_ / 32 - 1) __syncthreads();  // (3) swap buffers (drains prefetch)
  }

  // ---- epilogue: out = O / l for this wave's 256-d half ----
  float* ob = out + ((size_t)b * T_ + t0 + rg * 16) * D_ + h * 256;
#pragma unroll
  for (int r = 0; r < 4; ++r) {
    float inv = 1.f / O[16][r];
    const size_t rowoff = (size_t)(qd * 4 + r) * D_;
#pragma unroll
    for (int ng = 0; ng < 16; ++ng)
      ob[rowoff + ng * 16 + n] = O[ng][r] * inv;
  }
}

// ---------------------------------------------------------------------------
extern "C" void kernel_launch(void* const* d_in, const int* in_sizes, int n_in,
                              void* d_out, int out_size, void* d_ws, size_t ws_size,
                              hipStream_t stream) {
  (void)in_sizes; (void)n_in; (void)out_size; (void)ws_size;
  const float* main_in = (const float*)d_in[0];   // [B,T,D]
  const float* attn_in = (const float*)d_in[1];   // [B,S,D]
  const float* W_f     = (const float*)d_in[2];   // [D,D]
  const float* b_f     = (const float*)d_in[3];   // [D]
  float* out = (float*)d_out;                     // [B,T,D] fp32

  _Float16* K16 = (_Float16*)d_ws;                       // [B*S, D] fp16
  _Float16* Vt  = K16 + (size_t)B_ * S_ * D_;            // [B, D, S] fp16

  transpose_cast_kernel<<<dim3(D_ / 32, S_ / 32, B_), dim3(32, 8, 1), 0, stream>>>(
      attn_in, Vt);
  keys_gemm_kernel<<<dim3((B_ * S_) / 128, D_ / 128), 512, 0, stream>>>(
      attn_in, W_f, b_f, K16);
  flash_kernel<<<(B_ * T_) / 64, 512, 0, stream>>>(main_in, K16, Vt, out);
}